// Round 3
// baseline (209.490 us; speedup 1.0000x reference)
//
#include <hip/hip_runtime.h>
#include <hip/hip_bf16.h>

#define TB 8
#define TT 4096
#define TC 1024
#define THS 128

typedef __bf16 bf16;
typedef __attribute__((ext_vector_type(8))) __bf16 bf16x8;
typedef __attribute__((ext_vector_type(4))) __bf16 bf16x4;
typedef __attribute__((ext_vector_type(2))) __bf16 bf16x2;
typedef __attribute__((ext_vector_type(4))) float f32x4;
typedef __attribute__((ext_vector_type(16))) float f32x16;

__device__ __forceinline__ bf16 tobf(float f) {
    unsigned u = __builtin_bit_cast(unsigned, f);
    u += 0x7FFFu + ((u >> 16) & 1u);              // RNE
    unsigned short s = (unsigned short)(u >> 16);
    return __builtin_bit_cast(bf16, s);
}

__device__ __forceinline__ unsigned pkbf(float a, float b) {
    bf16x2 t = { (bf16)a, (bf16)b };              // RNE HW converts
    return __builtin_bit_cast(unsigned, t);
}

// ---- W cast+transpose: Wt[w][n][k] = bf16(W_w[k][n]) ----
__global__ __launch_bounds__(256) void wt_kernel(const float* __restrict__ Wq,
                                                 const float* __restrict__ Wk,
                                                 const float* __restrict__ Wv,
                                                 bf16* __restrict__ Wt) {
    int idx = blockIdx.x * 256 + threadIdx.x;     // [3][1024][128] as (w,k,n)
    int n = idx & 127;
    int k = (idx >> 7) & 1023;
    int w = idx >> 17;
    const float* W = (w == 0) ? Wq : (w == 1) ? Wk : Wv;
    Wt[((w << 7) + n) * 1024 + k] = tobf(W[(k << 7) + n]);
}

// ---- fused QKV projection: Q/K/V[b*T+t][d] bf16, q pre-scaled ----
__global__ __launch_bounds__(256) void qkv_kernel(const float* __restrict__ x,
                                                  const bf16* __restrict__ Wt,
                                                  bf16* __restrict__ Q,
                                                  bf16* __restrict__ K,
                                                  bf16* __restrict__ V) {
    __shared__ __align__(16) bf16 xt[64][40];
    __shared__ __align__(16) bf16 wt[3][128][40];
    const int tid = threadIdx.x;
    const int wave = tid >> 6, lane = tid & 63;
    const int g = lane >> 4, lr = lane & 15;
    const long row0 = (long)blockIdx.x * 64;

    f32x4 acc[3][8] = {};

    for (int k0 = 0; k0 < 1024; k0 += 32) {
        __syncthreads();
        #pragma unroll
        for (int i = 0; i < 2; i++) {                // x tile 64x32 f32->bf16
            int r = (tid >> 3) + 32 * i;
            int c4 = (tid & 7) * 4;
            const float4 xv = *reinterpret_cast<const float4*>(&x[(row0 + r) * 1024 + k0 + c4]);
            bf16x4 t;
            t[0] = tobf(xv.x); t[1] = tobf(xv.y); t[2] = tobf(xv.z); t[3] = tobf(xv.w);
            *reinterpret_cast<bf16x4*>(&xt[r][c4]) = t;
        }
        #pragma unroll
        for (int i = 0; i < 6; i++) {                // Wt tiles 3 x 128x32
            int slot = tid + 256 * i;
            int w = slot >> 9;
            int s = slot & 511;
            int n = s >> 2, c8 = (s & 3) * 8;
            *reinterpret_cast<bf16x8*>(&wt[w][n][c8]) =
                *reinterpret_cast<const bf16x8*>(&Wt[((w << 7) + n) * 1024 + k0 + c8]);
        }
        __syncthreads();
        bf16x8 a = *reinterpret_cast<const bf16x8*>(&xt[wave * 16 + lr][g * 8]);
        #pragma unroll
        for (int w = 0; w < 3; w++)
            #pragma unroll
            for (int nt = 0; nt < 8; nt++) {
                bf16x8 bfr = *reinterpret_cast<const bf16x8*>(&wt[w][nt * 16 + lr][g * 8]);
                acc[w][nt] = __builtin_amdgcn_mfma_f32_16x16x32_bf16(a, bfr, acc[w][nt], 0, 0, 0);
            }
    }
    const float qscale = 0.08838834764831845f;       // 128^-0.5
    bf16* outs[3] = {Q, K, V};
    #pragma unroll
    for (int w = 0; w < 3; w++)
        #pragma unroll
        for (int nt = 0; nt < 8; nt++)
            #pragma unroll
            for (int r = 0; r < 4; r++) {
                float v = acc[w][nt][r];
                if (w == 0) v *= qscale;
                long row = row0 + wave * 16 + g * 4 + r;   // C/D: col=lane&15, row=(lane>>4)*4+reg
                outs[w][row * 128 + nt * 16 + lr] = tobf(v);
            }
}

// ---- V transpose: Vt[b][d][t] = V[b][t][d] ----
__global__ __launch_bounds__(256) void vtrans_kernel(const bf16* __restrict__ V,
                                                     bf16* __restrict__ Vt) {
    __shared__ __align__(16) bf16 tile[64][136];
    const int tid = threadIdx.x;
    const int b = blockIdx.y;
    const int t0 = blockIdx.x * 64;
    const long ibase = ((long)b * TT + t0) * 128;
    #pragma unroll
    for (int i = 0; i < 4; i++) {
        int slot = tid + 256 * i;
        int r = slot >> 4, c8 = (slot & 15) * 8;
        *reinterpret_cast<bf16x8*>(&tile[r][c8]) =
            *reinterpret_cast<const bf16x8*>(&V[ibase + r * 128 + c8]);
    }
    __syncthreads();
    #pragma unroll
    for (int i = 0; i < 4; i++) {
        int slot = tid + 256 * i;
        int d = slot >> 3, t8 = (slot & 7) * 8;
        bf16x8 v;
        #pragma unroll
        for (int j = 0; j < 8; j++) v[j] = tile[t8 + j][d];
        *reinterpret_cast<bf16x8*>(&Vt[((long)b * 128 + d) * TT + t0 + t8]) = v;
    }
}

// ---- causal flash attention: swapped-operand 32x32x16, in-register softmax ----
// Block (qt, b): QBLK=64. 4 waves = (qhalf, kvparity): wave owns 32 q-rows (col side),
// processes KV tiles of 64 strided by parity, direct-from-global (K/Vt are L2-resident
// per XCD via blockIdx%8=batch). Parities merge at the end through LDS.
// Layouts (gfx950 mfma_f32_32x32x16_bf16):
//   A[row][k]: row=lane&31, k=(lane>>5)*8+j      B[k][col]: col=lane&31, k=(lane>>5)*8+j
//   C/D: col=lane&31, row=(reg&3)+8*(reg>>2)+4*(lane>>5)
__global__ __launch_bounds__(256, 1) void attn_kernel(const bf16* __restrict__ Q,
                                                      const bf16* __restrict__ K,
                                                      const bf16* __restrict__ Vt,
                                                      float* __restrict__ out) {
    __shared__ __align__(16) float om[2][32][132];   // merge O (qhalf), stride 132: 4-way banks, one-shot
    __shared__ float mm1[2][32], ll1[2][32];
    const int tid = threadIdx.x;
    const int wave = tid >> 6, lane = tid & 63;
    const int c = lane & 31, hi = lane >> 5;
    const int qh = wave & 1, kvp = wave >> 1;
    const int qt = 63 - (int)(blockIdx.x >> 3);      // big q-tiles first (balance)
    const int b = blockIdx.x & 7;                    // batch pinned to XCD
    const long base = (long)b * TT * 128;
    const long vbase = (long)b * 128 * TT;
    const int q0 = qt * 64 + qh * 32;
    const int qa = q0 + c;                           // this lane's q (column)

    bf16x8 qf[8];                                    // Q B-frags, natural [t][d] layout
    #pragma unroll
    for (int dw = 0; dw < 8; dw++)
        qf[dw] = *reinterpret_cast<const bf16x8*>(&Q[base + (long)qa * 128 + dw * 16 + hi * 8]);

    f32x16 O[4] = {};                                // O^T[d][q]: d = dt*32 + 8*(i>>2)+(i&3)+4*hi
    float m = -__builtin_inff(), l = 0.f;

    const int nt = qt + 1;
    #pragma unroll 1
    for (int t = kvp; t < nt; t += 2) {
        const int kv0 = t * 64;
        f32x16 S0 = {}, S1 = {};
        #pragma unroll
        for (int dw = 0; dw < 8; dw++) {             // S^T = K Q^T (two 32-kv subtiles)
            bf16x8 k0 = *reinterpret_cast<const bf16x8*>(
                &K[base + (long)(kv0 + c) * 128 + dw * 16 + hi * 8]);
            S0 = __builtin_amdgcn_mfma_f32_32x32x16_bf16(k0, qf[dw], S0, 0, 0, 0);
            bf16x8 k1 = *reinterpret_cast<const bf16x8*>(
                &K[base + (long)(kv0 + 32 + c) * 128 + dw * 16 + hi * 8]);
            S1 = __builtin_amdgcn_mfma_f32_32x32x16_bf16(k1, qf[dw], S1, 0, 0, 0);
        }
        if (t == qt) {                               // causal mask (diag tile only)
            #pragma unroll
            for (int i = 0; i < 16; i++) {
                int kvr = kv0 + (i & 3) + 8 * (i >> 2) + 4 * hi;
                if (kvr > qa)      S0[i] = -__builtin_inff();
                if (kvr + 32 > qa) S1[i] = -__builtin_inff();
            }
        }
        float t8[8];                                 // max tree (depth 5)
        #pragma unroll
        for (int i = 0; i < 8; i++)
            t8[i] = fmaxf(fmaxf(S0[i], S0[i + 8]), fmaxf(S1[i], S1[i + 8]));
        float t4a = fmaxf(t8[0], t8[4]), t4b = fmaxf(t8[1], t8[5]);
        float t4c = fmaxf(t8[2], t8[6]), t4d = fmaxf(t8[3], t8[7]);
        float pm = fmaxf(fmaxf(t4a, t4b), fmaxf(t4c, t4d));
        pm = fmaxf(pm, __shfl_xor(pm, 32, 64));      // partner half (other kv groups)
        if (!__all(pm - m <= 8.0f)) {                // defer-max: rescale only on real growth
            float mn = fmaxf(m, pm);
            float fr = __expf(m - mn);
            #pragma unroll
            for (int dt = 0; dt < 4; dt++) O[dt] = O[dt] * fr;
            l *= fr;
            m = mn;
        }
        #pragma unroll
        for (int i = 0; i < 16; i++) {               // P = exp(S - m), in place
            S0[i] = __expf(S0[i] - m);
            S1[i] = __expf(S1[i] - m);
        }
        float s8[8];                                 // sum tree (lane-partial l)
        #pragma unroll
        for (int i = 0; i < 8; i++)
            s8[i] = (S0[i] + S0[i + 8]) + (S1[i] + S1[i + 8]);
        l += ((s8[0] + s8[4]) + (s8[1] + s8[5])) + ((s8[2] + s8[6]) + (s8[3] + s8[7]));

        bf16x8 pf[4];                                // P -> B-frags: pack + half-exchange
        #pragma unroll
        for (int st = 0; st < 2; st++) {
            #pragma unroll
            for (int wl = 0; wl < 2; wl++) {
                const int i0 = 8 * wl;
                unsigned L0, L1, H0, H1;
                if (st == 0) {
                    L0 = pkbf(S0[i0 + 0], S0[i0 + 1]); L1 = pkbf(S0[i0 + 2], S0[i0 + 3]);
                    H0 = pkbf(S0[i0 + 4], S0[i0 + 5]); H1 = pkbf(S0[i0 + 6], S0[i0 + 7]);
                } else {
                    L0 = pkbf(S1[i0 + 0], S1[i0 + 1]); L1 = pkbf(S1[i0 + 2], S1[i0 + 3]);
                    H0 = pkbf(S1[i0 + 4], S1[i0 + 5]); H1 = pkbf(S1[i0 + 6], S1[i0 + 7]);
                }
                unsigned XL0 = __shfl_xor((int)L0, 32, 64);
                unsigned XL1 = __shfl_xor((int)L1, 32, 64);
                unsigned XH0 = __shfl_xor((int)H0, 32, 64);
                unsigned XH1 = __shfl_xor((int)H1, 32, 64);
                uint4 f;
                f.x = hi ? XH0 : L0;
                f.y = hi ? XH1 : L1;
                f.z = hi ? H0  : XL0;
                f.w = hi ? H1  : XL1;
                pf[st * 2 + wl] = __builtin_bit_cast(bf16x8, f);
            }
        }
        #pragma unroll
        for (int w = 0; w < 4; w++) {                // O^T += V^T P  (4 indep dt chains)
            #pragma unroll
            for (int dt = 0; dt < 4; dt++) {
                bf16x8 vf = *reinterpret_cast<const bf16x8*>(
                    &Vt[vbase + (long)(dt * 32 + c) * TT + kv0 + w * 16 + hi * 8]);
                O[dt] = __builtin_amdgcn_mfma_f32_32x32x16_bf16(vf, pf[w], O[dt], 0, 0, 0);
            }
        }
    }
    l += __shfl_xor(l, 32, 64);                      // combine partner kv-halves (same q)

    if (kvp == 1) {                                  // parity-1 publishes state
        #pragma unroll
        for (int dt = 0; dt < 4; dt++)
            #pragma unroll
            for (int g = 0; g < 4; g++) {
                float4 v = { O[dt][4 * g + 0], O[dt][4 * g + 1],
                             O[dt][4 * g + 2], O[dt][4 * g + 3] };
                *reinterpret_cast<float4*>(&om[qh][c][dt * 32 + 8 * g + 4 * hi]) = v;
            }
        if (hi == 0) { mm1[qh][c] = m; ll1[qh][c] = l; }
    }
    __syncthreads();
    if (kvp == 0) {                                  // parity-0 merges + writes out
        float m1 = mm1[qh][c], l1 = ll1[qh][c];
        float mx = fmaxf(m, m1);
        float f0 = __expf(m - mx);
        float f1 = __expf(m1 - mx);
        float linv = 1.0f / (l * f0 + l1 * f1);
        #pragma unroll
        for (int dt = 0; dt < 4; dt++)
            #pragma unroll
            for (int g = 0; g < 4; g++) {
                float4 o1 = *reinterpret_cast<const float4*>(&om[qh][c][dt * 32 + 8 * g + 4 * hi]);
                float4 r;
                r.x = (O[dt][4 * g + 0] * f0 + o1.x * f1) * linv;
                r.y = (O[dt][4 * g + 1] * f0 + o1.y * f1) * linv;
                r.z = (O[dt][4 * g + 2] * f0 + o1.z * f1) * linv;
                r.w = (O[dt][4 * g + 3] * f0 + o1.w * f1) * linv;
                *reinterpret_cast<float4*>(&out[base + (long)qa * 128 + dt * 32 + 8 * g + 4 * hi]) = r;
            }
    }
}

extern "C" void kernel_launch(void* const* d_in, const int* in_sizes, int n_in,
                              void* d_out, int out_size, void* d_ws, size_t ws_size,
                              hipStream_t stream) {
    const float* x  = (const float*)d_in[0];
    const float* Wq = (const float*)d_in[1];
    const float* Wk = (const float*)d_in[2];
    const float* Wv = (const float*)d_in[3];
    float* out = (float*)d_out;
    bf16* Q  = (bf16*)d_ws;                       // [32768][128]
    bf16* K  = Q  + (size_t)32768 * 128;
    bf16* V  = K  + (size_t)32768 * 128;
    bf16* Wt = V  + (size_t)32768 * 128;          // [3][128][1024]
    bf16* Vt = Wt + (size_t)3 * 128 * 1024;       // [8][128][4096]
    wt_kernel<<<1536, 256, 0, stream>>>(Wq, Wk, Wv, Wt);
    qkv_kernel<<<512, 256, 0, stream>>>(x, Wt, Q, K, V);
    vtrans_kernel<<<dim3(64, 8), 256, 0, stream>>>(V, Vt);
    attn_kernel<<<512, 256, 0, stream>>>(Q, K, Vt, out);
}

// Round 4
// 158.308 us; speedup vs baseline: 1.3233x; 1.3233x over previous
//
#include <hip/hip_runtime.h>
#include <hip/hip_bf16.h>

#define TB 8
#define TT 4096
#define TC 1024
#define THS 128

typedef __bf16 bf16;
typedef __attribute__((ext_vector_type(8))) __bf16 bf16x8;
typedef __attribute__((ext_vector_type(4))) __bf16 bf16x4;
typedef __attribute__((ext_vector_type(2))) __bf16 bf16x2;
typedef __attribute__((ext_vector_type(4))) float f32x4;
typedef __attribute__((ext_vector_type(16))) float f32x16;

__device__ __forceinline__ bf16 tobf(float f) {
    unsigned u = __builtin_bit_cast(unsigned, f);
    u += 0x7FFFu + ((u >> 16) & 1u);              // RNE
    unsigned short s = (unsigned short)(u >> 16);
    return __builtin_bit_cast(bf16, s);
}

__device__ __forceinline__ unsigned pkbf(float a, float b) {
    bf16x2 t = { (bf16)a, (bf16)b };
    return __builtin_bit_cast(unsigned, t);
}

__device__ __forceinline__ void gload16(const void* g, void* l) {
    __builtin_amdgcn_global_load_lds(
        (const __attribute__((address_space(1))) void*)g,
        (__attribute__((address_space(3))) void*)l, 16, 0, 0);
}

// ---- W cast+transpose: Wt[w][n][k] = bf16(W_w[k][n]) ----
__global__ __launch_bounds__(256) void wt_kernel(const float* __restrict__ Wq,
                                                 const float* __restrict__ Wk,
                                                 const float* __restrict__ Wv,
                                                 bf16* __restrict__ Wt) {
    int idx = blockIdx.x * 256 + threadIdx.x;
    int n = idx & 127;
    int k = (idx >> 7) & 1023;
    int w = idx >> 17;
    const float* W = (w == 0) ? Wq : (w == 1) ? Wk : Wv;
    Wt[((w << 7) + n) * 1024 + k] = tobf(W[(k << 7) + n]);
}

// ---- fused QKV projection ----
__global__ __launch_bounds__(256) void qkv_kernel(const float* __restrict__ x,
                                                  const bf16* __restrict__ Wt,
                                                  bf16* __restrict__ Q,
                                                  bf16* __restrict__ K,
                                                  bf16* __restrict__ V) {
    __shared__ __align__(16) bf16 xt[64][40];
    __shared__ __align__(16) bf16 wt[3][128][40];
    const int tid = threadIdx.x;
    const int wave = tid >> 6, lane = tid & 63;
    const int g = lane >> 4, lr = lane & 15;
    const long row0 = (long)blockIdx.x * 64;

    f32x4 acc[3][8] = {};

    for (int k0 = 0; k0 < 1024; k0 += 32) {
        __syncthreads();
        #pragma unroll
        for (int i = 0; i < 2; i++) {
            int r = (tid >> 3) + 32 * i;
            int c4 = (tid & 7) * 4;
            const float4 xv = *reinterpret_cast<const float4*>(&x[(row0 + r) * 1024 + k0 + c4]);
            bf16x4 t;
            t[0] = tobf(xv.x); t[1] = tobf(xv.y); t[2] = tobf(xv.z); t[3] = tobf(xv.w);
            *reinterpret_cast<bf16x4*>(&xt[r][c4]) = t;
        }
        #pragma unroll
        for (int i = 0; i < 6; i++) {
            int slot = tid + 256 * i;
            int w = slot >> 9;
            int s = slot & 511;
            int n = s >> 2, c8 = (s & 3) * 8;
            *reinterpret_cast<bf16x8*>(&wt[w][n][c8]) =
                *reinterpret_cast<const bf16x8*>(&Wt[((w << 7) + n) * 1024 + k0 + c8]);
        }
        __syncthreads();
        bf16x8 a = *reinterpret_cast<const bf16x8*>(&xt[wave * 16 + lr][g * 8]);
        #pragma unroll
        for (int w = 0; w < 3; w++)
            #pragma unroll
            for (int nt = 0; nt < 8; nt++) {
                bf16x8 bfr = *reinterpret_cast<const bf16x8*>(&wt[w][nt * 16 + lr][g * 8]);
                acc[w][nt] = __builtin_amdgcn_mfma_f32_16x16x32_bf16(a, bfr, acc[w][nt], 0, 0, 0);
            }
    }
    const float qscale = 0.08838834764831845f;
    bf16* outs[3] = {Q, K, V};
    #pragma unroll
    for (int w = 0; w < 3; w++)
        #pragma unroll
        for (int nt = 0; nt < 8; nt++)
            #pragma unroll
            for (int r = 0; r < 4; r++) {
                float v = acc[w][nt][r];
                if (w == 0) v *= qscale;
                long row = row0 + wave * 16 + g * 4 + r;
                outs[w][row * 128 + nt * 16 + lr] = tobf(v);
            }
}

// ---- V transpose: Vt[b][d][t] = V[b][t][d] ----
__global__ __launch_bounds__(256) void vtrans_kernel(const bf16* __restrict__ V,
                                                     bf16* __restrict__ Vt) {
    __shared__ __align__(16) bf16 tile[64][136];
    const int tid = threadIdx.x;
    const int b = blockIdx.y;
    const int t0 = blockIdx.x * 64;
    const long ibase = ((long)b * TT + t0) * 128;
    #pragma unroll
    for (int i = 0; i < 4; i++) {
        int slot = tid + 256 * i;
        int r = slot >> 4, c8 = (slot & 15) * 8;
        *reinterpret_cast<bf16x8*>(&tile[r][c8]) =
            *reinterpret_cast<const bf16x8*>(&V[ibase + r * 128 + c8]);
    }
    __syncthreads();
    #pragma unroll
    for (int i = 0; i < 4; i++) {
        int slot = tid + 256 * i;
        int d = slot >> 3, t8 = (slot & 7) * 8;
        bf16x8 v;
        #pragma unroll
        for (int j = 0; j < 8; j++) v[j] = tile[t8 + j][d];
        *reinterpret_cast<bf16x8*>(&Vt[((long)b * 128 + d) * TT + t0 + t8]) = v;
    }
}

// ---- causal flash attention, flash-decoding split + LDS-pipelined tiles ----
// Block (v,b), v in [0,32): phase1 = item v, phase2 = item 63-v; item u -> (qt=u>>1, h=u&1).
// Item (qt,h): q rows [128qt,128qt+128), kv tiles t in [h*(qt+1), (h+1)*(qt+1)), KVB=64.
// Chains sum to exactly 33 tiles per block; 256 blocks = 1/CU.
// K/V staged to LDS via global_load_lds (pre-swizzled source, swizzled ds_read: rule #21),
// double-buffered, issue-early/drain-late. Partial (O,m,l) per item -> merge kernel.
__global__ __launch_bounds__(256, 1) void attn_kernel(const bf16* __restrict__ Q,
                                                      const bf16* __restrict__ K,
                                                      const bf16* __restrict__ Vt,
                                                      float* __restrict__ pO,
                                                      float* __restrict__ pML) {
    __shared__ __align__(1024) bf16 kbuf[2][64 * 128];    // [kv][d] rows 256B, XOR-swizzled
    __shared__ __align__(1024) bf16 vbuf[2][128 * 64];    // [d][kv] rows 128B, XOR-swizzled
    const int tid = threadIdx.x;
    const int wave = tid >> 6, lane = tid & 63;
    const int c = lane & 31, hi = lane >> 5;
    const int ksw = (c & 7) << 4;
    const int v = blockIdx.x >> 3;
    const int b = blockIdx.x & 7;                          // batch pinned to XCD
    const long base = (long)b * TT * 128;
    const char* Kb = (const char*)(K + base);
    const char* Vb = (const char*)(Vt + (long)b * 128 * TT);

    long kOff[4], vOff[4];                                 // pre-swizzled global src offsets
    int lOff[4];
    #pragma unroll
    for (int i = 0; i < 4; i++) {
        int D = wave * 4096 + i * 1024 + lane * 16;        // linear LDS dest byte
        int kr = D >> 8, kcb = D & 255;
        kOff[i] = (long)kr * 256 + (kcb ^ ((kr & 7) << 4));
        int vr = D >> 7, vcb = D & 127;
        vOff[i] = (long)vr * 8192 + (vcb ^ ((vr & 7) << 4));
        lOff[i] = wave * 4096 + i * 1024;
    }

    #pragma unroll 1
    for (int ph = 0; ph < 2; ph++) {
        const int u = (ph == 0) ? v : 63 - v;
        const int qt = u >> 1, h = u & 1;
        const int t0 = h * (qt + 1), t1 = (h + 1) * (qt + 1);
        const int q0w = qt * 128 + wave * 32;
        const int qa = q0w + c;

        {   // stage tile t0 into buffer 0
            const char* Ks = Kb + (long)t0 * 16384;
            const char* Vs = Vb + (long)t0 * 128;
            #pragma unroll
            for (int i = 0; i < 4; i++) {
                gload16(Ks + kOff[i], (char*)&kbuf[0][0] + lOff[i]);
                gload16(Vs + vOff[i], (char*)&vbuf[0][0] + lOff[i]);
            }
        }
        bf16x8 qf[8];
        #pragma unroll
        for (int dw = 0; dw < 8; dw++)
            qf[dw] = *reinterpret_cast<const bf16x8*>(&Q[base + (long)qa * 128 + dw * 16 + hi * 8]);

        f32x16 O[4] = {};
        float m = -__builtin_inff(), l = 0.f;

        asm volatile("s_waitcnt vmcnt(0)" ::: "memory");
        __builtin_amdgcn_s_barrier();

        #pragma unroll 1
        for (int t = t0; t < t1; t++) {
            const int cur = (t - t0) & 1;
            if (t + 1 < t1) {                              // issue next-tile stage (overlaps compute)
                const char* Ks = Kb + (long)(t + 1) * 16384;
                const char* Vs = Vb + (long)(t + 1) * 128;
                #pragma unroll
                for (int i = 0; i < 4; i++) {
                    gload16(Ks + kOff[i], (char*)&kbuf[cur ^ 1][0] + lOff[i]);
                    gload16(Vs + vOff[i], (char*)&vbuf[cur ^ 1][0] + lOff[i]);
                }
            }
            const int kv0 = t * 64;
            if (kv0 <= q0w + 31) {                         // wave has unmasked work
                const char* kb = (const char*)&kbuf[cur][0];
                const char* vb = (const char*)&vbuf[cur][0];
                f32x16 S0 = {}, S1 = {};
                #pragma unroll
                for (int dw = 0; dw < 8; dw++) {           // S^T = K Q^T
                    bf16x8 k0 = *reinterpret_cast<const bf16x8*>(
                        kb + c * 256 + ((dw * 32 + hi * 16) ^ ksw));
                    S0 = __builtin_amdgcn_mfma_f32_32x32x16_bf16(k0, qf[dw], S0, 0, 0, 0);
                    bf16x8 k1 = *reinterpret_cast<const bf16x8*>(
                        kb + 8192 + c * 256 + ((dw * 32 + hi * 16) ^ ksw));
                    S1 = __builtin_amdgcn_mfma_f32_32x32x16_bf16(k1, qf[dw], S1, 0, 0, 0);
                }
                if (kv0 + 63 > q0w) {                      // causal mask near diagonal
                    #pragma unroll
                    for (int i = 0; i < 16; i++) {
                        int kvr = kv0 + (i & 3) + 8 * (i >> 2) + 4 * hi;
                        if (kvr > qa)      S0[i] = -__builtin_inff();
                        if (kvr + 32 > qa) S1[i] = -__builtin_inff();
                    }
                }
                float t8[8];
                #pragma unroll
                for (int i = 0; i < 8; i++)
                    t8[i] = fmaxf(fmaxf(S0[i], S0[i + 8]), fmaxf(S1[i], S1[i + 8]));
                float t4a = fmaxf(t8[0], t8[4]), t4b = fmaxf(t8[1], t8[5]);
                float t4c = fmaxf(t8[2], t8[6]), t4d = fmaxf(t8[3], t8[7]);
                float pm = fmaxf(fmaxf(t4a, t4b), fmaxf(t4c, t4d));
                pm = fmaxf(pm, __shfl_xor(pm, 32, 64));
                if (!__all(pm - m <= 8.0f)) {              // defer-max
                    float mn = fmaxf(m, pm);
                    float fr = __expf(m - mn);
                    #pragma unroll
                    for (int dt = 0; dt < 4; dt++) O[dt] = O[dt] * fr;
                    l *= fr;
                    m = mn;
                }
                #pragma unroll
                for (int i = 0; i < 16; i++) {
                    S0[i] = __expf(S0[i] - m);
                    S1[i] = __expf(S1[i] - m);
                }
                float s8[8];
                #pragma unroll
                for (int i = 0; i < 8; i++)
                    s8[i] = (S0[i] + S0[i + 8]) + (S1[i] + S1[i + 8]);
                l += ((s8[0] + s8[4]) + (s8[1] + s8[5])) + ((s8[2] + s8[6]) + (s8[3] + s8[7]));

                bf16x8 pf[4];                              // P -> B-frags (pack + half-exchange)
                #pragma unroll
                for (int st = 0; st < 2; st++) {
                    #pragma unroll
                    for (int wl = 0; wl < 2; wl++) {
                        const int i0 = 8 * wl;
                        unsigned L0, L1, H0, H1;
                        if (st == 0) {
                            L0 = pkbf(S0[i0 + 0], S0[i0 + 1]); L1 = pkbf(S0[i0 + 2], S0[i0 + 3]);
                            H0 = pkbf(S0[i0 + 4], S0[i0 + 5]); H1 = pkbf(S0[i0 + 6], S0[i0 + 7]);
                        } else {
                            L0 = pkbf(S1[i0 + 0], S1[i0 + 1]); L1 = pkbf(S1[i0 + 2], S1[i0 + 3]);
                            H0 = pkbf(S1[i0 + 4], S1[i0 + 5]); H1 = pkbf(S1[i0 + 6], S1[i0 + 7]);
                        }
                        unsigned XL0 = __shfl_xor((int)L0, 32, 64);
                        unsigned XL1 = __shfl_xor((int)L1, 32, 64);
                        unsigned XH0 = __shfl_xor((int)H0, 32, 64);
                        unsigned XH1 = __shfl_xor((int)H1, 32, 64);
                        uint4 f;
                        f.x = hi ? XH0 : L0;
                        f.y = hi ? XH1 : L1;
                        f.z = hi ? H0  : XL0;
                        f.w = hi ? H1  : XL1;
                        pf[st * 2 + wl] = __builtin_bit_cast(bf16x8, f);
                    }
                }
                #pragma unroll
                for (int w = 0; w < 4; w++)                // O^T += V^T P
                    #pragma unroll
                    for (int dt = 0; dt < 4; dt++) {
                        bf16x8 vf = *reinterpret_cast<const bf16x8*>(
                            vb + dt * 4096 + c * 128 + ((w * 32 + hi * 16) ^ ksw));
                        O[dt] = __builtin_amdgcn_mfma_f32_32x32x16_bf16(vf, pf[w], O[dt], 0, 0, 0);
                    }
            }
            asm volatile("s_waitcnt vmcnt(0)" ::: "memory");   // next tile landed (issued pre-compute)
            __builtin_amdgcn_s_barrier();
        }

        l += __shfl_xor(l, 32, 64);                        // combine hi-half partials (same q)
        const int pidx = (b * 32 + qt) * 2 + h;
        if (hi == 0) {
            pML[(long)pidx * 256 + wave * 32 + c] = m;
            pML[(long)pidx * 256 + 128 + wave * 32 + c] = l;
        }
        float* po = pO + (long)pidx * 16384 + (long)(wave * 32 + c) * 128;
        #pragma unroll
        for (int dt = 0; dt < 4; dt++)
            #pragma unroll
            for (int g = 0; g < 4; g++) {
                float4 w4 = { O[dt][4 * g + 0], O[dt][4 * g + 1],
                              O[dt][4 * g + 2], O[dt][4 * g + 3] };
                *reinterpret_cast<float4*>(&po[dt * 32 + 8 * g + 4 * hi]) = w4;
            }
    }
}

// ---- merge the two kv-halves of each q-tile ----
__global__ __launch_bounds__(256) void merge_kernel(const float* __restrict__ pO,
                                                    const float* __restrict__ pML,
                                                    float* __restrict__ out) {
    const int blk = blockIdx.x;                            // qt*8 + b
    const int qt = blk >> 3, b = blk & 7;
    const int tid = threadIdx.x;
    const int qr = tid >> 1;
    const int dh = (tid & 1) * 64;
    const long pidx0 = (long)(b * 32 + qt) * 2;
    const float* s0 = pML + pidx0 * 256;
    const float* s1 = s0 + 256;
    float m0 = s0[qr], l0 = s0[128 + qr];
    float m1 = s1[qr], l1 = s1[128 + qr];
    float mx = fmaxf(m0, m1);
    float f0 = __expf(m0 - mx), f1 = __expf(m1 - mx);
    float linv = 1.0f / (l0 * f0 + l1 * f1);
    const float* o0 = pO + pidx0 * 16384 + (long)qr * 128 + dh;
    const float* o1 = o0 + 16384;
    float* op = out + (long)b * TT * 128 + (long)(qt * 128 + qr) * 128 + dh;
    #pragma unroll
    for (int i = 0; i < 16; i++) {
        float4 a = *reinterpret_cast<const float4*>(&o0[i * 4]);
        float4 c4 = *reinterpret_cast<const float4*>(&o1[i * 4]);
        float4 r;
        r.x = (a.x * f0 + c4.x * f1) * linv;
        r.y = (a.y * f0 + c4.y * f1) * linv;
        r.z = (a.z * f0 + c4.z * f1) * linv;
        r.w = (a.w * f0 + c4.w * f1) * linv;
        *reinterpret_cast<float4*>(&op[i * 4]) = r;
    }
}

extern "C" void kernel_launch(void* const* d_in, const int* in_sizes, int n_in,
                              void* d_out, int out_size, void* d_ws, size_t ws_size,
                              hipStream_t stream) {
    const float* x  = (const float*)d_in[0];
    const float* Wq = (const float*)d_in[1];
    const float* Wk = (const float*)d_in[2];
    const float* Wv = (const float*)d_in[3];
    float* out = (float*)d_out;
    bf16* Q  = (bf16*)d_ws;                       // [32768][128]
    bf16* K  = Q  + (size_t)32768 * 128;
    bf16* V  = K  + (size_t)32768 * 128;
    bf16* Wt = V  + (size_t)32768 * 128;          // [3][128][1024]
    bf16* Vt = Wt + (size_t)3 * 128 * 1024;       // [8][128][4096]
    float* pO  = (float*)(Vt + (size_t)8 * 128 * 4096);   // [512][128][128]
    float* pML = pO + (size_t)512 * 16384;                // [512][2][128]
    wt_kernel<<<1536, 256, 0, stream>>>(Wq, Wk, Wv, Wt);
    qkv_kernel<<<512, 256, 0, stream>>>(x, Wt, Q, K, V);
    vtrans_kernel<<<dim3(64, 8), 256, 0, stream>>>(V, Vt);
    attn_kernel<<<256, 256, 0, stream>>>(Q, K, Vt, pO, pML);
    merge_kernel<<<256, 256, 0, stream>>>(pO, pML, out);
}

// Round 5
// 137.785 us; speedup vs baseline: 1.5204x; 1.1490x over previous
//
#include <hip/hip_runtime.h>
#include <hip/hip_bf16.h>

#define TB 8
#define TT 4096
#define TC 1024
#define THS 128

typedef __bf16 bf16;
typedef __attribute__((ext_vector_type(8))) __bf16 bf16x8;
typedef __attribute__((ext_vector_type(2))) __bf16 bf16x2;
typedef __attribute__((ext_vector_type(4))) float f32x4;
typedef __attribute__((ext_vector_type(16))) float f32x16;

__device__ __forceinline__ unsigned pkbf(float a, float b) {
    bf16x2 t = { (bf16)a, (bf16)b };
    return __builtin_bit_cast(unsigned, t);
}

__device__ __forceinline__ void gload16(const void* g, void* l) {
    __builtin_amdgcn_global_load_lds(
        (const __attribute__((address_space(1))) void*)g,
        (__attribute__((address_space(3))) void*)l, 16, 0, 0);
}

// ---- W cast+transpose: Wt[w][n][k] = bf16(W_w[k][n]) ----
__global__ __launch_bounds__(256) void wt_kernel(const float* __restrict__ Wq,
                                                 const float* __restrict__ Wk,
                                                 const float* __restrict__ Wv,
                                                 bf16* __restrict__ Wt) {
    int idx = blockIdx.x * 256 + threadIdx.x;
    int n = idx & 127;
    int k = (idx >> 7) & 1023;
    int w = idx >> 17;
    const float* W = (w == 0) ? Wq : (w == 1) ? Wk : Wv;
    Wt[((w << 7) + n) * 1024 + k] = (bf16)W[(k << 7) + n];
}

// ---- fused QKV projection: 64 rows x 384 cols per block, wave = 64x96 ----
// All staging via global_load_lds (x as raw f32, Wt bf16), XOR-swizzled sources,
// double-buffered, one vmcnt(0)+barrier per BK=32 step. 64KB LDS -> 2 blocks/CU.
__global__ __launch_bounds__(256, 2) void qkv_kernel(const float* __restrict__ x,
                                                     const bf16* __restrict__ Wt,
                                                     bf16* __restrict__ Q,
                                                     bf16* __restrict__ K,
                                                     bf16* __restrict__ V) {
    __shared__ __align__(1024) char wsm[2][24576];   // Wt tile [384][32] bf16, 64B rows
    __shared__ __align__(1024) char xsm[2][8192];    // x tile [64][32] f32, 128B rows
    const int tid = threadIdx.x;
    const int wave = tid >> 6, lane = tid & 63;
    const int lr = lane & 15, g = lane >> 4;
    const long row0 = (long)blockIdx.x * 64;

    long wOff[6]; int wLoff[6];
    #pragma unroll
    for (int i = 0; i < 6; i++) {
        int D = i * 4096 + wave * 1024 + lane * 16;
        int n = D >> 6, kb2 = D & 63;
        wOff[i] = (long)n * 2048 + (kb2 ^ ((n & 3) << 4));
        wLoff[i] = i * 4096 + wave * 1024;
    }
    long xOff[2]; int xLoff[2];
    #pragma unroll
    for (int i = 0; i < 2; i++) {
        int D = wave * 2048 + i * 1024 + lane * 16;
        int xr = D >> 7, xcb = D & 127;
        xOff[i] = (long)xr * 4096 + (xcb ^ ((xr & 7) << 4));
        xLoff[i] = wave * 2048 + i * 1024;
    }
    const char* xb = (const char*)x + row0 * 4096;
    const char* wb = (const char*)Wt;

    f32x4 acc[4][6] = {};

    {   // prologue: stage k0=0 into buf 0
        #pragma unroll
        for (int i = 0; i < 6; i++) gload16(wb + wOff[i], &wsm[0][0] + wLoff[i]);
        #pragma unroll
        for (int i = 0; i < 2; i++) gload16(xb + xOff[i], &xsm[0][0] + xLoff[i]);
    }
    asm volatile("s_waitcnt vmcnt(0)" ::: "memory");
    __builtin_amdgcn_s_barrier();

    const int asw = (lr & 7) << 4;
    const int bsw = (lr & 3) << 4;
    #pragma unroll 1
    for (int s = 0; s < 32; s++) {
        const int bi = s & 1;
        if (s + 1 < 32) {                            // issue next stage (overlaps compute)
            const char* wsrc = wb + (long)(s + 1) * 64;      // k0*2 bytes
            const char* xsrc = xb + (long)(s + 1) * 128;     // k0*4 bytes
            #pragma unroll
            for (int i = 0; i < 6; i++) gload16(wsrc + wOff[i], &wsm[bi ^ 1][0] + wLoff[i]);
            #pragma unroll
            for (int i = 0; i < 2; i++) gload16(xsrc + xOff[i], &xsm[bi ^ 1][0] + xLoff[i]);
        }
        const char* xp = &xsm[bi][0];
        const char* wp = &wsm[bi][0];
        bf16x8 a[4];
        #pragma unroll
        for (int ar = 0; ar < 4; ar++) {             // A-frags from f32 LDS + convert
            const int rbase = (ar * 16 + lr) * 128;
            f32x4 lo = *reinterpret_cast<const f32x4*>(xp + rbase + ((g * 32) ^ asw));
            f32x4 hi4 = *reinterpret_cast<const f32x4*>(xp + rbase + ((g * 32 + 16) ^ asw));
            uint4 u;
            u.x = pkbf(lo[0], lo[1]); u.y = pkbf(lo[2], lo[3]);
            u.z = pkbf(hi4[0], hi4[1]); u.w = pkbf(hi4[2], hi4[3]);
            a[ar] = __builtin_bit_cast(bf16x8, u);
        }
        #pragma unroll
        for (int nt = 0; nt < 6; nt++) {
            const int n = wave * 96 + nt * 16 + lr;
            bf16x8 bfr = *reinterpret_cast<const bf16x8*>(wp + n * 64 + ((g * 16) ^ bsw));
            #pragma unroll
            for (int ar = 0; ar < 4; ar++)
                acc[ar][nt] = __builtin_amdgcn_mfma_f32_16x16x32_bf16(a[ar], bfr, acc[ar][nt], 0, 0, 0);
        }
        asm volatile("s_waitcnt vmcnt(0)" ::: "memory");
        __builtin_amdgcn_s_barrier();
    }
    const float qscale = 0.08838834764831845f;       // 128^-0.5
    bf16* outs[3] = {Q, K, V};
    #pragma unroll
    for (int nt = 0; nt < 6; nt++) {
        const int col = wave * 96 + nt * 16 + lr;
        const int w = col >> 7, d = col & 127;
        #pragma unroll
        for (int ar = 0; ar < 4; ar++)
            #pragma unroll
            for (int r = 0; r < 4; r++) {
                float val = acc[ar][nt][r];
                if (w == 0) val *= qscale;
                long row = row0 + ar * 16 + g * 4 + r;
                outs[w][row * 128 + d] = (bf16)val;
            }
    }
}

// ---- V transpose: Vt[b][d][t] = V[b][t][d] ----
__global__ __launch_bounds__(256) void vtrans_kernel(const bf16* __restrict__ V,
                                                     bf16* __restrict__ Vt) {
    __shared__ __align__(16) bf16 tile[64][136];
    const int tid = threadIdx.x;
    const int b = blockIdx.y;
    const int t0 = blockIdx.x * 64;
    const long ibase = ((long)b * TT + t0) * 128;
    #pragma unroll
    for (int i = 0; i < 4; i++) {
        int slot = tid + 256 * i;
        int r = slot >> 4, c8 = (slot & 15) * 8;
        *reinterpret_cast<bf16x8*>(&tile[r][c8]) =
            *reinterpret_cast<const bf16x8*>(&V[ibase + r * 128 + c8]);
    }
    __syncthreads();
    #pragma unroll
    for (int i = 0; i < 4; i++) {
        int slot = tid + 256 * i;
        int d = slot >> 3, t8 = (slot & 7) * 8;
        bf16x8 v;
        #pragma unroll
        for (int j = 0; j < 8; j++) v[j] = tile[t8 + j][d];
        *reinterpret_cast<bf16x8*>(&Vt[((long)b * 128 + d) * TT + t0 + t8]) = v;
    }
}

// ---- causal flash attention: 8 waves = 2 q-segs x 4 kv-quarters, in-block merge ----
// Block (v,b): phase1 qt=v, phase2 qt=63-v (64-row q-tiles, qt in [0,64)).
// Quarter qq takes KVB=32 tiles t == qq (mod 4); per-block iterations ~17 uniform.
// 4x dbuf staging via global_load_lds (128KB LDS, 1 block/CU, 2 waves/SIMD).
// Quarters merge (m,l,O) through LDS at phase end; out written directly.
__global__ __launch_bounds__(512, 2) void attn_kernel(const bf16* __restrict__ Q,
                                                      const bf16* __restrict__ K,
                                                      const bf16* __restrict__ Vt,
                                                      float* __restrict__ out) {
    __shared__ __align__(1024) char smem[131072];
    const int tid = threadIdx.x;
    const int wave = tid >> 6, lane = tid & 63;
    const int c = lane & 31, hi = lane >> 5;
    const int qs = wave & 1, qq = wave >> 1;
    const int ksw = (c & 7) << 4, vsw = (c & 3) << 4;
    const int v = blockIdx.x >> 3, b = blockIdx.x & 7;   // batch pinned to XCD
    const long base = (long)b * TT * 128;
    const char* Kb = (const char*)(K + base);
    const char* Vb = (const char*)(Vt + (long)b * 128 * TT);
    char* kB[2] = { smem + qq * 16384, smem + qq * 16384 + 8192 };
    char* vB[2] = { smem + 65536 + qq * 16384, smem + 65536 + qq * 16384 + 8192 };
    float* mm = (float*)(smem + 98304);                  // [6][32]
    float* ll = (float*)(smem + 99072);                  // [6][32]

    long kOff[4], vOff[4]; int lOff[4];
    #pragma unroll
    for (int i = 0; i < 4; i++) {
        int D = qs * 4096 + i * 1024 + lane * 16;
        int kr = D >> 8, kcb = D & 255;                  // K rows 256B
        kOff[i] = kr * 256 + (kcb ^ ((kr & 7) << 4));
        int vr = D >> 6, vcb = D & 63;                   // V^T rows 64B
        vOff[i] = (long)vr * 8192 + (vcb ^ ((vr & 3) << 4));
        lOff[i] = qs * 4096 + i * 1024;
    }

    #pragma unroll 1
    for (int ph = 0; ph < 2; ph++) {
        const int qt = ph ? 63 - v : v;
        const int ntile = 2 * (qt + 1);                  // KVB=32 tiles
        const int nIt = (ntile + 3) >> 2;
        const int q0w = qt * 64 + qs * 32;
        const int qa = q0w + c;

        bf16x8 qf[8];
        #pragma unroll
        for (int dw = 0; dw < 8; dw++)
            qf[dw] = *reinterpret_cast<const bf16x8*>(&Q[base + (long)qa * 128 + dw * 16 + hi * 8]);

        f32x16 O[4] = {};
        float m = -__builtin_inff(), l = 0.f;

        if (qq < ntile) {                                // prologue: stage tile qq -> buf0
            const char* Ks = Kb + (long)qq * 8192;
            const char* Vs = Vb + (long)qq * 64;
            #pragma unroll
            for (int i = 0; i < 4; i++) {
                gload16(Ks + kOff[i], kB[0] + lOff[i]);
                gload16(Vs + vOff[i], vB[0] + lOff[i]);
            }
        }
        asm volatile("s_waitcnt vmcnt(0)" ::: "memory");
        __builtin_amdgcn_s_barrier();

        #pragma unroll 1
        for (int it = 0; it < nIt; it++) {
            const int bi = it & 1;
            const int t = qq + 4 * it;
            const int tn = t + 4;
            if (tn < ntile) {                            // issue next stage (overlaps compute)
                const char* Ks = Kb + (long)tn * 8192;
                const char* Vs = Vb + (long)tn * 64;
                #pragma unroll
                for (int i = 0; i < 4; i++) {
                    gload16(Ks + kOff[i], kB[bi ^ 1] + lOff[i]);
                    gload16(Vs + vOff[i], vB[bi ^ 1] + lOff[i]);
                }
            }
            const int kv0 = t * 32;
            if (t < ntile && kv0 <= q0w + 31) {
                const char* kb = kB[bi];
                const char* vb = vB[bi];
                f32x16 S = {};
                #pragma unroll
                for (int dw = 0; dw < 8; dw++) {         // S^T = K Q^T
                    bf16x8 kf = *reinterpret_cast<const bf16x8*>(
                        kb + c * 256 + ((dw * 32 + hi * 16) ^ ksw));
                    S = __builtin_amdgcn_mfma_f32_32x32x16_bf16(kf, qf[dw], S, 0, 0, 0);
                }
                if (kv0 + 31 > q0w) {                    // causal mask near diagonal
                    #pragma unroll
                    for (int i = 0; i < 16; i++) {
                        int kvr = kv0 + (i & 3) + 8 * (i >> 2) + 4 * hi;
                        if (kvr > qa) S[i] = -__builtin_inff();
                    }
                }
                float t8[8];
                #pragma unroll
                for (int i = 0; i < 8; i++) t8[i] = fmaxf(S[i], S[i + 8]);
                float t4a = fmaxf(t8[0], t8[4]), t4b = fmaxf(t8[1], t8[5]);
                float t4c = fmaxf(t8[2], t8[6]), t4d = fmaxf(t8[3], t8[7]);
                float pm = fmaxf(fmaxf(t4a, t4b), fmaxf(t4c, t4d));
                pm = fmaxf(pm, __shfl_xor(pm, 32, 64));  // partner holds other 16 kv rows
                if (!__all(pm - m <= 8.0f)) {            // defer-max
                    float mn = fmaxf(m, pm);
                    float fr = __expf(m - mn);
                    #pragma unroll
                    for (int dt = 0; dt < 4; dt++) O[dt] = O[dt] * fr;
                    l *= fr;
                    m = mn;
                }
                #pragma unroll
                for (int i = 0; i < 16; i++) S[i] = __expf(S[i] - m);
                float s8[8];
                #pragma unroll
                for (int i = 0; i < 8; i++) s8[i] = S[i] + S[i + 8];
                l += ((s8[0] + s8[4]) + (s8[1] + s8[5])) + ((s8[2] + s8[6]) + (s8[3] + s8[7]));

                bf16x8 pf[2];                            // P -> B-frags (pack + half-exchange)
                #pragma unroll
                for (int wl = 0; wl < 2; wl++) {
                    const int i0 = 8 * wl;
                    unsigned L0 = pkbf(S[i0 + 0], S[i0 + 1]);
                    unsigned L1 = pkbf(S[i0 + 2], S[i0 + 3]);
                    unsigned H0 = pkbf(S[i0 + 4], S[i0 + 5]);
                    unsigned H1 = pkbf(S[i0 + 6], S[i0 + 7]);
                    unsigned XL0 = __shfl_xor((int)L0, 32, 64);
                    unsigned XL1 = __shfl_xor((int)L1, 32, 64);
                    unsigned XH0 = __shfl_xor((int)H0, 32, 64);
                    unsigned XH1 = __shfl_xor((int)H1, 32, 64);
                    uint4 f;
                    f.x = hi ? XH0 : L0;
                    f.y = hi ? XH1 : L1;
                    f.z = hi ? H0 : XL0;
                    f.w = hi ? H1 : XL1;
                    pf[wl] = __builtin_bit_cast(bf16x8, f);
                }
                #pragma unroll
                for (int wl = 0; wl < 2; wl++)           // O^T += V^T P
                    #pragma unroll
                    for (int dt = 0; dt < 4; dt++) {
                        bf16x8 vf = *reinterpret_cast<const bf16x8*>(
                            vb + (dt * 32 + c) * 64 + ((wl * 32 + hi * 16) ^ vsw));
                        O[dt] = __builtin_amdgcn_mfma_f32_32x32x16_bf16(vf, pf[wl], O[dt], 0, 0, 0);
                    }
            }
            asm volatile("s_waitcnt vmcnt(0)" ::: "memory");
            __builtin_amdgcn_s_barrier();
        }

        l += __shfl_xor(l, 32, 64);                      // combine partner kv-row halves

        if (qq != 0) {                                   // quarters 1..3 publish partials
            const int sl = (qq - 1) * 2 + qs;
            char* om = smem + sl * 16384;
            #pragma unroll
            for (int dt = 0; dt < 4; dt++)
                #pragma unroll
                for (int g = 0; g < 4; g++) {
                    float4 w4 = { O[dt][4 * g + 0], O[dt][4 * g + 1],
                                  O[dt][4 * g + 2], O[dt][4 * g + 3] };
                    *reinterpret_cast<float4*>(
                        om + c * 512 + ((dt * 128 + g * 32 + hi * 16) ^ ((c & 7) << 4))) = w4;
                }
            if (hi == 0) { mm[sl * 32 + c] = m; ll[sl * 32 + c] = l; }
        }
        __syncthreads();
        if (qq == 0) {                                   // quarter 0 merges + writes out
            float mq[3], lq[3];
            float mx = m;
            #pragma unroll
            for (int p = 0; p < 3; p++) {
                const int sl = p * 2 + qs;
                mq[p] = mm[sl * 32 + c];
                lq[p] = ll[sl * 32 + c];
                mx = fmaxf(mx, mq[p]);
            }
            float f0 = __expf(m - mx);
            float lt = l * f0;
            float fq[3];
            #pragma unroll
            for (int p = 0; p < 3; p++) { fq[p] = __expf(mq[p] - mx); lt += lq[p] * fq[p]; }
            float linv = 1.0f / lt;
            #pragma unroll
            for (int dt = 0; dt < 4; dt++)
                #pragma unroll
                for (int g = 0; g < 4; g++) {
                    float4 r;
                    r.x = O[dt][4 * g + 0] * f0;
                    r.y = O[dt][4 * g + 1] * f0;
                    r.z = O[dt][4 * g + 2] * f0;
                    r.w = O[dt][4 * g + 3] * f0;
                    #pragma unroll
                    for (int p = 0; p < 3; p++) {
                        const char* om = smem + (p * 2 + qs) * 16384;
                        float4 o1 = *reinterpret_cast<const float4*>(
                            om + c * 512 + ((dt * 128 + g * 32 + hi * 16) ^ ((c & 7) << 4)));
                        r.x += o1.x * fq[p]; r.y += o1.y * fq[p];
                        r.z += o1.z * fq[p]; r.w += o1.w * fq[p];
                    }
                    r.x *= linv; r.y *= linv; r.z *= linv; r.w *= linv;
                    *reinterpret_cast<float4*>(
                        &out[base + (long)qa * 128 + dt * 32 + 8 * g + 4 * hi]) = r;
                }
        }
        __syncthreads();                                 // LDS safe before next phase stages
    }
}

extern "C" void kernel_launch(void* const* d_in, const int* in_sizes, int n_in,
                              void* d_out, int out_size, void* d_ws, size_t ws_size,
                              hipStream_t stream) {
    const float* x  = (const float*)d_in[0];
    const float* Wq = (const float*)d_in[1];
    const float* Wk = (const float*)d_in[2];
    const float* Wv = (const float*)d_in[3];
    float* out = (float*)d_out;
    bf16* Q  = (bf16*)d_ws;                       // [32768][128]
    bf16* K  = Q  + (size_t)32768 * 128;
    bf16* V  = K  + (size_t)32768 * 128;
    bf16* Wt = V  + (size_t)32768 * 128;          // [3][128][1024]
    bf16* Vt = Wt + (size_t)3 * 128 * 1024;       // [8][128][4096]
    wt_kernel<<<1536, 256, 0, stream>>>(Wq, Wk, Wv, Wt);
    qkv_kernel<<<512, 256, 0, stream>>>(x, Wt, Q, K, V);
    vtrans_kernel<<<dim3(64, 8), 256, 0, stream>>>(V, Vt);
    attn_kernel<<<256, 512, 0, stream>>>(Q, K, Vt, out);
}